// Round 1
// baseline (360.264 us; speedup 1.0000x reference)
//
#include <hip/hip_runtime.h>
#include <math.h>

#define BB 8
#define FF 256
#define SS 1024
#define KK 16
#define ITERS 5

// ---------- wm[b][j] = mean_i w[b][i][j] ----------
__global__ void wm_kernel(const float* __restrict__ w, float* __restrict__ wm) {
    int t = blockIdx.x * blockDim.x + threadIdx.x;  // over B*S
    if (t >= BB * SS) return;
    int b = t / SS, j = t % SS;
    const float* wp = w + (size_t)b * SS * SS + j;
    float s = 0.f;
    for (int i = 0; i < SS; ++i) s += wp[(size_t)i * SS];
    wm[t] = s * (1.0f / SS);
}

// ---------- d[b][i][j] = sum_f |x[b][f][i] - x[b][f][j]| ----------
#define TS 64
#define FC 16
__global__ __launch_bounds__(256) void dist_kernel(const float* __restrict__ x,
                                                   float* __restrict__ d) {
    __shared__ float As[FC][TS];
    __shared__ float Bs[FC][TS];
    int b = blockIdx.z;
    int i0 = blockIdx.y * TS;
    int j0 = blockIdx.x * TS;
    int tid = threadIdx.x;
    int tx = tid & 15, ty = tid >> 4;
    const float* xb = x + (size_t)b * FF * SS;
    float acc[4][4] = {};
    for (int f0 = 0; f0 < FF; f0 += FC) {
        for (int r = 0; r < 4; ++r) {
            int l = tid + r * 256;
            int f = l >> 6, tok = l & 63;
            As[f][tok] = xb[(size_t)(f0 + f) * SS + i0 + tok];
            Bs[f][tok] = xb[(size_t)(f0 + f) * SS + j0 + tok];
        }
        __syncthreads();
#pragma unroll
        for (int f = 0; f < FC; ++f) {
            float4 a = *(const float4*)&As[f][ty * 4];
            float4 bb = *(const float4*)&Bs[f][tx * 4];
            float av[4] = {a.x, a.y, a.z, a.w};
            float bv[4] = {bb.x, bb.y, bb.z, bb.w};
#pragma unroll
            for (int r = 0; r < 4; ++r)
#pragma unroll
                for (int c = 0; c < 4; ++c)
                    acc[r][c] += fabsf(av[r] - bv[c]);
        }
        __syncthreads();
    }
    for (int r = 0; r < 4; ++r) {
        float4 v = make_float4(acc[r][0], acc[r][1], acc[r][2], acc[r][3]);
        *(float4*)&d[(size_t)b * SS * SS + (size_t)(i0 + ty * 4 + r) * SS + j0 + tx * 4] = v;
    }
}

// ---------- initial medoids: top-K of wm, jax.lax.top_k semantics ----------
__global__ void topk_kernel(const float* __restrict__ wm, int* __restrict__ ctr) {
    int b = blockIdx.x;
    __shared__ float vals[SS];
    __shared__ float rv[256];
    __shared__ int ri[256];
    int tid = threadIdx.x;
    for (int j = tid; j < SS; j += 256) vals[j] = wm[b * SS + j];
    __syncthreads();
    for (int k = 0; k < KK; ++k) {
        float bv = -INFINITY;
        int bi = 0x7fffffff;
        for (int j = tid; j < SS; j += 256) {
            float v = vals[j];
            if (v > bv) { bv = v; bi = j; }   // strict > keeps first (lowest j)
        }
        rv[tid] = bv; ri[tid] = bi;
        __syncthreads();
        for (int s = 128; s > 0; s >>= 1) {
            if (tid < s) {
                if (rv[tid + s] > rv[tid] ||
                    (rv[tid + s] == rv[tid] && ri[tid + s] < ri[tid])) {
                    rv[tid] = rv[tid + s];
                    ri[tid] = ri[tid + s];
                }
            }
            __syncthreads();
        }
        if (tid == 0) {
            ctr[b * KK + k] = ri[0];
            vals[ri[0]] = -INFINITY;
        }
        __syncthreads();
    }
}

// ---------- assign[b][i] = argmin_k d[b][i][ctr[b][k]] (first-k tiebreak) ----------
// d is exactly symmetric, so read d[ctr][i] (coalesced over i).
__global__ void assign_kernel(const float* __restrict__ d, const int* __restrict__ ctr,
                              int* __restrict__ assign) {
    int t = blockIdx.x * blockDim.x + threadIdx.x;
    if (t >= BB * SS) return;
    int b = t / SS, i = t % SS;
    const float* db = d + (size_t)b * SS * SS;
    const int* cb = ctr + b * KK;
    float bv = INFINITY;
    int bk = 0;
#pragma unroll
    for (int k = 0; k < KK; ++k) {
        float v = db[(size_t)cb[k] * SS + i];
        if (v < bv) { bv = v; bk = k; }   // strict < keeps first k
    }
    assign[t] = bk;
}

// ---------- cost[b][i] = sum_{j: assign[j]==assign[i]} d[i][j]*wm[j] ----------
__global__ __launch_bounds__(256) void cost_kernel(const float* __restrict__ d,
                                                   const float* __restrict__ wm,
                                                   const int* __restrict__ assign,
                                                   float* __restrict__ cost) {
    int b = blockIdx.y;
    int i = blockIdx.x;
    int tid = threadIdx.x;
    int my = assign[b * SS + i];
    const float* drow = d + (size_t)b * SS * SS + (size_t)i * SS;
    const float* wb = wm + b * SS;
    const int* ab = assign + b * SS;
    float4 dv = *(const float4*)&drow[tid * 4];
    float4 wv = *(const float4*)&wb[tid * 4];
    int4 av = *(const int4*)&ab[tid * 4];
    float s = 0.f;
    s += (av.x == my) ? dv.x * wv.x : 0.f;
    s += (av.y == my) ? dv.y * wv.y : 0.f;
    s += (av.z == my) ? dv.z * wv.z : 0.f;
    s += (av.w == my) ? dv.w * wv.w : 0.f;
#pragma unroll
    for (int off = 32; off > 0; off >>= 1) s += __shfl_down(s, off, 64);
    __shared__ float ws_s[4];
    if ((tid & 63) == 0) ws_s[tid >> 6] = s;
    __syncthreads();
    if (tid == 0) cost[b * SS + i] = (ws_s[0] + ws_s[1]) + (ws_s[2] + ws_s[3]);
}

// ---------- ctr[b][k] = argmin_{i: assign[i]==k} cost[b][i]; empty -> 0 ----------
__global__ void update_kernel(const float* __restrict__ cost, const int* __restrict__ assign,
                              int* __restrict__ ctr) {
    int b = blockIdx.y, k = blockIdx.x;
    int tid = threadIdx.x;
    __shared__ float rv[256];
    __shared__ int ri[256];
    float bv = INFINITY;
    int bi = 0x7fffffff;
    for (int i = tid; i < SS; i += 256) {
        if (assign[b * SS + i] == k) {
            float v = cost[b * SS + i];
            if (v < bv || (v == bv && i < bi)) { bv = v; bi = i; }
        }
    }
    rv[tid] = bv; ri[tid] = bi;
    __syncthreads();
    for (int s = 128; s > 0; s >>= 1) {
        if (tid < s) {
            if (rv[tid + s] < rv[tid] ||
                (rv[tid + s] == rv[tid] && ri[tid + s] < ri[tid])) {
                rv[tid] = rv[tid + s];
                ri[tid] = ri[tid + s];
            }
        }
        __syncthreads();
    }
    if (tid == 0) ctr[b * KK + k] = (ri[0] == 0x7fffffff) ? 0 : ri[0];
}

// ---------- out[b][f][k] = x[b][f][ctr[b][k]] ----------
__global__ void gather_kernel(const float* __restrict__ x, const int* __restrict__ ctr,
                              float* __restrict__ out) {
    int t = blockIdx.x * blockDim.x + threadIdx.x;
    if (t >= BB * FF * KK) return;
    int b = t / (FF * KK);
    int f = (t / KK) % FF;
    int k = t % KK;
    out[t] = x[(size_t)b * FF * SS + (size_t)f * SS + ctr[b * KK + k]];
}

extern "C" void kernel_launch(void* const* d_in, const int* in_sizes, int n_in,
                              void* d_out, int out_size, void* d_ws, size_t ws_size,
                              hipStream_t stream) {
    const float* x = (const float*)d_in[0];   // [B,F,S]
    const float* w = (const float*)d_in[1];   // [B,S,S]
    float* out = (float*)d_out;               // [B,F,K]

    char* ws = (char*)d_ws;
    float* d = (float*)ws;                              // B*S*S floats = 33.55 MB
    size_t off = (size_t)BB * SS * SS * sizeof(float);
    float* wm = (float*)(ws + off);  off += (size_t)BB * SS * sizeof(float);
    int* ctr = (int*)(ws + off);     off += (size_t)BB * KK * sizeof(int);
    int* assign = (int*)(ws + off);  off += (size_t)BB * SS * sizeof(int);
    float* cost = (float*)(ws + off);

    wm_kernel<<<(BB * SS + 255) / 256, 256, 0, stream>>>(w, wm);
    dist_kernel<<<dim3(SS / TS, SS / TS, BB), 256, 0, stream>>>(x, d);
    topk_kernel<<<BB, 256, 0, stream>>>(wm, ctr);
    for (int it = 0; it < ITERS; ++it) {
        assign_kernel<<<(BB * SS + 255) / 256, 256, 0, stream>>>(d, ctr, assign);
        cost_kernel<<<dim3(SS, BB), 256, 0, stream>>>(d, wm, assign, cost);
        update_kernel<<<dim3(KK, BB), 256, 0, stream>>>(cost, assign, ctr);
    }
    gather_kernel<<<(BB * FF * KK + 255) / 256, 256, 0, stream>>>(x, ctr, out);
}

// Round 2
// 271.727 us; speedup vs baseline: 1.3258x; 1.3258x over previous
//
#include <hip/hip_runtime.h>
#include <math.h>

#define BB 8
#define FF 256
#define SS 1024
#define KK 16
#define ITERS 5

// ---------- wm: two-stage deterministic column-mean of w ----------
// Stage 1: partial sums over i-chunks (grid: S/256 x ICH x B)
#define ICH 8
__global__ void wm_part_kernel(const float* __restrict__ w, float* __restrict__ part) {
    int j = blockIdx.x * 256 + threadIdx.x;
    int ic = blockIdx.y, b = blockIdx.z;
    const float* wp = w + (size_t)b * SS * SS + (size_t)ic * (SS / ICH) * SS + j;
    float s = 0.f;
#pragma unroll 8
    for (int i = 0; i < SS / ICH; ++i) s += wp[(size_t)i * SS];
    part[((size_t)ic * BB + b) * SS + j] = s;
}

__global__ void wm_final_kernel(const float* __restrict__ part, float* __restrict__ wm) {
    int t = blockIdx.x * blockDim.x + threadIdx.x;
    if (t >= BB * SS) return;
    int b = t / SS, j = t % SS;
    float s = 0.f;
#pragma unroll
    for (int ic = 0; ic < ICH; ++ic) s += part[((size_t)ic * BB + b) * SS + j];
    wm[t] = s * (1.0f / SS);
}

// ---------- d[b][i][j] = sum_f |x[b][f][i] - x[b][f][j]| ----------
// d is bitwise symmetric (same f-order accumulation for (i,j) and (j,i)),
// so compute only tiles with j_tile >= i_tile and mirror via LDS transpose.
#define TS 64
#define FC 16
__global__ __launch_bounds__(256) void dist_kernel(const float* __restrict__ x,
                                                   float* __restrict__ d) {
    // LDS: As/Bs staging (8 KB) unioned with the 64x65 transpose tile (16.6 KB)
    __shared__ float smbuf[TS * (TS + 1)];
    float (*As)[TS] = reinterpret_cast<float(*)[TS]>(smbuf);
    float (*Bs)[TS] = reinterpret_cast<float(*)[TS]>(smbuf + FC * TS);
    float (*tr)[TS + 1] = reinterpret_cast<float(*)[TS + 1]>(smbuf);

    int b = blockIdx.y;
    // decode triangular tile index: 136 tiles, j_t >= i_t
    int t = blockIdx.x;
    int it = 0;
    while (t >= (SS / TS) - it) { t -= (SS / TS) - it; ++it; }
    int jt = it + t;
    int i0 = it * TS;
    int j0 = jt * TS;

    int tid = threadIdx.x;
    int tx = tid & 15, ty = tid >> 4;
    const float* xb = x + (size_t)b * FF * SS;
    float* db = d + (size_t)b * SS * SS;
    float acc[4][4] = {};
    for (int f0 = 0; f0 < FF; f0 += FC) {
#pragma unroll
        for (int r = 0; r < 4; ++r) {
            int l = tid + r * 256;
            int f = l >> 6, tok = l & 63;
            As[f][tok] = xb[(size_t)(f0 + f) * SS + i0 + tok];
            Bs[f][tok] = xb[(size_t)(f0 + f) * SS + j0 + tok];
        }
        __syncthreads();
#pragma unroll
        for (int f = 0; f < FC; ++f) {
            float4 a = *(const float4*)&As[f][ty * 4];
            float4 bb = *(const float4*)&Bs[f][tx * 4];
            float av[4] = {a.x, a.y, a.z, a.w};
            float bv[4] = {bb.x, bb.y, bb.z, bb.w};
#pragma unroll
            for (int r = 0; r < 4; ++r)
#pragma unroll
                for (int c = 0; c < 4; ++c)
                    acc[r][c] += fabsf(av[r] - bv[c]);
        }
        __syncthreads();
    }
    // direct tile write (rows i0.., cols j0..), coalesced float4
#pragma unroll
    for (int r = 0; r < 4; ++r) {
        float4 v = make_float4(acc[r][0], acc[r][1], acc[r][2], acc[r][3]);
        *(float4*)&db[(size_t)(i0 + ty * 4 + r) * SS + j0 + tx * 4] = v;
    }
    if (jt != it) {
        // mirrored tile (rows j0.., cols i0..) via LDS transpose
#pragma unroll
        for (int r = 0; r < 4; ++r)
#pragma unroll
            for (int c = 0; c < 4; ++c)
                tr[tx * 4 + c][ty * 4 + r] = acc[r][c];
        __syncthreads();
#pragma unroll
        for (int q = 0; q < 4; ++q) {
            int row = q * 16 + (tid >> 4);
            int col = (tid & 15) * 4;
            float4 v;
            v.x = tr[row][col];
            v.y = tr[row][col + 1];
            v.z = tr[row][col + 2];
            v.w = tr[row][col + 3];
            *(float4*)&db[(size_t)(j0 + row) * SS + i0 + col] = v;
        }
    }
}

// ---------- initial medoids: top-K of wm, jax.lax.top_k semantics ----------
__global__ void topk_kernel(const float* __restrict__ wm, int* __restrict__ ctr) {
    int b = blockIdx.x;
    __shared__ float vals[SS];
    __shared__ float rv[256];
    __shared__ int ri[256];
    int tid = threadIdx.x;
    for (int j = tid; j < SS; j += 256) vals[j] = wm[b * SS + j];
    __syncthreads();
    for (int k = 0; k < KK; ++k) {
        float bv = -INFINITY;
        int bi = 0x7fffffff;
        for (int j = tid; j < SS; j += 256) {
            float v = vals[j];
            if (v > bv) { bv = v; bi = j; }   // strict > keeps first (lowest j)
        }
        rv[tid] = bv; ri[tid] = bi;
        __syncthreads();
        for (int s = 128; s > 0; s >>= 1) {
            if (tid < s) {
                if (rv[tid + s] > rv[tid] ||
                    (rv[tid + s] == rv[tid] && ri[tid + s] < ri[tid])) {
                    rv[tid] = rv[tid + s];
                    ri[tid] = ri[tid + s];
                }
            }
            __syncthreads();
        }
        if (tid == 0) {
            ctr[b * KK + k] = ri[0];
            vals[ri[0]] = -INFINITY;
        }
        __syncthreads();
    }
}

// ---------- assign[b][i] = argmin_k d[b][i][ctr[b][k]] (first-k tiebreak) ----------
// d is exactly symmetric, so read d[ctr][i] (coalesced over i).
__global__ void assign_kernel(const float* __restrict__ d, const int* __restrict__ ctr,
                              int* __restrict__ assign) {
    int t = blockIdx.x * blockDim.x + threadIdx.x;
    if (t >= BB * SS) return;
    int b = t / SS, i = t % SS;
    const float* db = d + (size_t)b * SS * SS;
    const int* cb = ctr + b * KK;
    float bv = INFINITY;
    int bk = 0;
#pragma unroll
    for (int k = 0; k < KK; ++k) {
        float v = db[(size_t)cb[k] * SS + i];
        if (v < bv) { bv = v; bk = k; }   // strict < keeps first k
    }
    assign[t] = bk;
}

// ---------- cost[b][i] = sum_{j: assign[j]==assign[i]} d[i][j]*wm[j] ----------
__global__ __launch_bounds__(256) void cost_kernel(const float* __restrict__ d,
                                                   const float* __restrict__ wm,
                                                   const int* __restrict__ assign,
                                                   float* __restrict__ cost) {
    int b = blockIdx.y;
    int i = blockIdx.x;
    int tid = threadIdx.x;
    int my = assign[b * SS + i];
    const float* drow = d + (size_t)b * SS * SS + (size_t)i * SS;
    const float* wb = wm + b * SS;
    const int* ab = assign + b * SS;
    float4 dv = *(const float4*)&drow[tid * 4];
    float4 wv = *(const float4*)&wb[tid * 4];
    int4 av = *(const int4*)&ab[tid * 4];
    float s = 0.f;
    s += (av.x == my) ? dv.x * wv.x : 0.f;
    s += (av.y == my) ? dv.y * wv.y : 0.f;
    s += (av.z == my) ? dv.z * wv.z : 0.f;
    s += (av.w == my) ? dv.w * wv.w : 0.f;
#pragma unroll
    for (int off = 32; off > 0; off >>= 1) s += __shfl_down(s, off, 64);
    __shared__ float ws_s[4];
    if ((tid & 63) == 0) ws_s[tid >> 6] = s;
    __syncthreads();
    if (tid == 0) cost[b * SS + i] = (ws_s[0] + ws_s[1]) + (ws_s[2] + ws_s[3]);
}

// ---------- ctr[b][k] = argmin_{i: assign[i]==k} cost[b][i]; empty -> 0 ----------
__global__ void update_kernel(const float* __restrict__ cost, const int* __restrict__ assign,
                              int* __restrict__ ctr) {
    int b = blockIdx.y, k = blockIdx.x;
    int tid = threadIdx.x;
    __shared__ float rv[256];
    __shared__ int ri[256];
    float bv = INFINITY;
    int bi = 0x7fffffff;
    for (int i = tid; i < SS; i += 256) {
        if (assign[b * SS + i] == k) {
            float v = cost[b * SS + i];
            if (v < bv || (v == bv && i < bi)) { bv = v; bi = i; }
        }
    }
    rv[tid] = bv; ri[tid] = bi;
    __syncthreads();
    for (int s = 128; s > 0; s >>= 1) {
        if (tid < s) {
            if (rv[tid + s] < rv[tid] ||
                (rv[tid + s] == rv[tid] && ri[tid + s] < ri[tid])) {
                rv[tid] = rv[tid + s];
                ri[tid] = ri[tid + s];
            }
        }
        __syncthreads();
    }
    if (tid == 0) ctr[b * KK + k] = (ri[0] == 0x7fffffff) ? 0 : ri[0];
}

// ---------- out[b][f][k] = x[b][f][ctr[b][k]] ----------
__global__ void gather_kernel(const float* __restrict__ x, const int* __restrict__ ctr,
                              float* __restrict__ out) {
    int t = blockIdx.x * blockDim.x + threadIdx.x;
    if (t >= BB * FF * KK) return;
    int b = t / (FF * KK);
    int f = (t / KK) % FF;
    int k = t % KK;
    out[t] = x[(size_t)b * FF * SS + (size_t)f * SS + ctr[b * KK + k]];
}

extern "C" void kernel_launch(void* const* d_in, const int* in_sizes, int n_in,
                              void* d_out, int out_size, void* d_ws, size_t ws_size,
                              hipStream_t stream) {
    const float* x = (const float*)d_in[0];   // [B,F,S]
    const float* w = (const float*)d_in[1];   // [B,S,S]
    float* out = (float*)d_out;               // [B,F,K]

    char* ws = (char*)d_ws;
    float* d = (float*)ws;                              // B*S*S floats = 33.55 MB
    size_t off = (size_t)BB * SS * SS * sizeof(float);
    float* wm = (float*)(ws + off);  off += (size_t)BB * SS * sizeof(float);
    int* ctr = (int*)(ws + off);     off += (size_t)BB * KK * sizeof(int);
    int* assign = (int*)(ws + off);  off += (size_t)BB * SS * sizeof(int);
    float* cost = (float*)(ws + off);
    // wm_part scratch aliases d: wm_final consumes it before dist_kernel
    // writes d (same stream => serialized).
    float* part = (float*)ws;

    wm_part_kernel<<<dim3(SS / 256, ICH, BB), 256, 0, stream>>>(w, part);
    wm_final_kernel<<<(BB * SS + 255) / 256, 256, 0, stream>>>(part, wm);
    // 136 = (S/TS)*(S/TS+1)/2 triangular tiles per batch
    dist_kernel<<<dim3(136, BB), 256, 0, stream>>>(x, d);
    topk_kernel<<<BB, 256, 0, stream>>>(wm, ctr);
    for (int itr = 0; itr < ITERS; ++itr) {
        assign_kernel<<<(BB * SS + 255) / 256, 256, 0, stream>>>(d, ctr, assign);
        cost_kernel<<<dim3(SS, BB), 256, 0, stream>>>(d, wm, assign, cost);
        update_kernel<<<dim3(KK, BB), 256, 0, stream>>>(cost, assign, ctr);
    }
    gather_kernel<<<(BB * FF * KK + 255) / 256, 256, 0, stream>>>(x, ctr, out);
}